// Round 7
// baseline (91.314 us; speedup 1.0000x reference)
//
#include <hip/hip_runtime.h>

namespace {
constexpr int kB = 1024;
constexpr int kN = 40;
constexpr int kE = 64;
constexpr int kP = kN * (kN - 1) / 2;  // 780

using bf16x8 = __attribute__((ext_vector_type(8))) short;
using f32x4  = __attribute__((ext_vector_type(4))) float;

__device__ inline unsigned short f2bf(float x) {  // RNE fp32->bf16
  union { float f; unsigned u; } v; v.f = x;
  return (unsigned short)((v.u + 0x7FFFu + ((v.u >> 16) & 1u)) >> 16);
}
__device__ inline float bf2f(unsigned short u) {
  union { unsigned u; float f; } v; v.u = (unsigned)u << 16;
  return v.f;
}

// ---- fused prep (unchanged from R6, proven) ----
// blocks [0, 640): x (B,N,E) fp32 -> B-frag layout xf:
//   per (n,bg): 1024 shorts [ks:2][lane:64][j:8] = x[bg*16+(L&15)][n][ks*32+(L>>4)*8+j]
// blocks [640, 1420): param -> A-frag layout Af: per pair i: 4096 shorts,
//   chunk (mt*2+ks)*512 + L*8 holds M_i[16mt+(L&15)][ks*32+(L>>4)*8+j]
__global__ __launch_bounds__(256) void prep(const float* __restrict__ in,
                                            const float* __restrict__ param,
                                            unsigned short* __restrict__ xf,
                                            unsigned short* __restrict__ Af) {
  __shared__ short Ms[64 * 72];
  const int t = threadIdx.x;
  if (blockIdx.x < 640) {
    const int n    = blockIdx.x >> 4;
    const int bgc  = blockIdx.x & 15;
    const int bgl  = t >> 6;
    const int L    = t & 63;
    const int col  = L & 15;
    const int quad = L >> 4;
    const int b    = (bgc * 4 + bgl) * 16 + col;
    const float* src    = in + ((size_t)b * kN + n) * kE + quad * 8;
    unsigned short* dst = xf + (((size_t)n * 64 + bgc * 4 + bgl) << 10) + L * 8;
    const float4 v0 = ((const float4*)src)[0];
    const float4 v1 = ((const float4*)src)[1];
    const float4 v2 = ((const float4*)(src + 32))[0];
    const float4 v3 = ((const float4*)(src + 32))[1];
    bf16x8 o0, o1;
    o0[0] = (short)f2bf(v0.x); o0[1] = (short)f2bf(v0.y);
    o0[2] = (short)f2bf(v0.z); o0[3] = (short)f2bf(v0.w);
    o0[4] = (short)f2bf(v1.x); o0[5] = (short)f2bf(v1.y);
    o0[6] = (short)f2bf(v1.z); o0[7] = (short)f2bf(v1.w);
    o1[0] = (short)f2bf(v2.x); o1[1] = (short)f2bf(v2.y);
    o1[2] = (short)f2bf(v2.z); o1[3] = (short)f2bf(v2.w);
    o1[4] = (short)f2bf(v3.x); o1[5] = (short)f2bf(v3.y);
    o1[6] = (short)f2bf(v3.z); o1[7] = (short)f2bf(v3.w);
    *(bf16x8*)dst         = o0;
    *(bf16x8*)(dst + 512) = o1;
  } else {
    const int i = blockIdx.x - 640;  // pair index
#pragma unroll
    for (int ph = 0; ph < 4; ++ph) {
      const int f  = ph * 16 + (t >> 4);
      const int e0 = (t & 15) * 4;
      const float4 v = *(const float4*)(param + ((size_t)f * kP + i) * kE + e0);
      short* d = &Ms[f * 72 + e0];
      d[0] = (short)f2bf(v.x); d[1] = (short)f2bf(v.y);
      d[2] = (short)f2bf(v.z); d[3] = (short)f2bf(v.w);
    }
    __syncthreads();
    unsigned short* base = Af + (size_t)i * 4096;
#pragma unroll
    for (int u = 0; u < 2; ++u) {
      const int chunk = t * 2 + u;       // 0..511
      const int L    = chunk & 63;
      const int mtks = chunk >> 6;
      const int mt   = mtks >> 1, ks = mtks & 1;
      const int col  = L & 15, quad = L >> 4;
      const bf16x8 a = *(const bf16x8*)&Ms[(16 * mt + col) * 72 + ks * 32 + quad * 8];
      *(bf16x8*)(base + chunk * 8) = a;
    }
  }
}

// ---- main: block = 2r x 4c node tile (8 pairs, 8 waves) x 256 batches.
// Node tiling halves p/q L3 traffic vs pair-per-wave-no-tile (6 rows feed 8 pairs).
// All loads dense (Af A-frags, xf B-frags/q); 16-deep reg double-buffer per wave.
__global__ __launch_bounds__(512, 4)
void opn_tile2(const unsigned short* __restrict__ xf,
               const unsigned short* __restrict__ Af,
               float* __restrict__ out) {  // (B,1,P) fp32
  __shared__ float dots[2][256][4];  // [rr][b_local][cc], 8 KB

  const int t    = threadIdx.x;
  const int w    = t >> 6;
  const int L    = t & 63;
  const int col  = L & 15;
  const int quad = L >> 4;

  // tile decode (R4-proven): r-group a -> rows 2a,2a+1; c-group cb -> cols 4cb..+3
  int a = 0, tx = blockIdx.x;
  for (;;) { const int nb = 10 - ((2 * a + 1) >> 2); if (tx < nb) break; tx -= nb; ++a; }
  const int cb  = ((2 * a + 1) >> 2) + tx;
  const int r0  = 2 * a, c0 = 4 * cb;
  const int gb0 = blockIdx.y * 256;

  const int rr = w >> 2, cc = w & 3;
  const int r = r0 + rr, c = c0 + cc;

  if (c > r) {
    const int i = r * (79 - r) / 2 + c - r - 1;

    // A-frags: 8 dense 16B loads (R2-HW-verified mapping)
    const unsigned short* ab = Af + (size_t)i * 4096 + L * 8;
    bf16x8 A[4][2];
#pragma unroll
    for (int mt = 0; mt < 4; ++mt)
#pragma unroll
      for (int ks = 0; ks < 2; ++ks)
        A[mt][ks] = *(const bf16x8*)(ab + (mt * 2 + ks) * 512);

    const int bgg0 = blockIdx.y * 16;
    const unsigned short* pb = xf + (((size_t)r * 64 + bgg0) << 10);
    const unsigned short* qb = xf + (((size_t)c * 64 + bgg0) << 10);
    const int qoff = (quad >> 1) * 128 + col * 8 + (quad & 1) * 4;  // R5-proven

    bf16x8 B0[2], B1[2];
    ushort4 Q[2][4];
    B0[0]   = *(const bf16x8*)(pb + L * 8);
    B1[0]   = *(const bf16x8*)(pb + 512 + L * 8);
    Q[0][0] = *(const ushort4*)(qb + qoff);
    Q[0][1] = *(const ushort4*)(qb + 256 + qoff);
    Q[0][2] = *(const ushort4*)(qb + 512 + qoff);
    Q[0][3] = *(const ushort4*)(qb + 768 + qoff);

#pragma unroll
    for (int bg = 0; bg < 16; ++bg) {
      const int cbi = bg & 1, nbi = cbi ^ 1;
      if (bg < 15) {  // prefetch next bg into alternate regs
        const unsigned short* pn = pb + ((size_t)(bg + 1) << 10);
        const unsigned short* qn = qb + ((size_t)(bg + 1) << 10);
        B0[nbi]   = *(const bf16x8*)(pn + L * 8);
        B1[nbi]   = *(const bf16x8*)(pn + 512 + L * 8);
        Q[nbi][0] = *(const ushort4*)(qn + qoff);
        Q[nbi][1] = *(const ushort4*)(qn + 256 + qoff);
        Q[nbi][2] = *(const ushort4*)(qn + 512 + qoff);
        Q[nbi][3] = *(const ushort4*)(qn + 768 + qoff);
      }
      f32x4 acc[4];
#pragma unroll
      for (int mt = 0; mt < 4; ++mt) acc[mt] = (f32x4){0.f, 0.f, 0.f, 0.f};
#pragma unroll
      for (int mt = 0; mt < 4; ++mt) {
        acc[mt] = __builtin_amdgcn_mfma_f32_16x16x32_bf16(A[mt][0], B0[cbi], acc[mt], 0, 0, 0);
        acc[mt] = __builtin_amdgcn_mfma_f32_16x16x32_bf16(A[mt][1], B1[cbi], acc[mt], 0, 0, 0);
      }
      float s[4];
#pragma unroll
      for (int mt = 0; mt < 4; ++mt) {
        const ushort4 qu = Q[cbi][mt];
        float sm;
        sm = acc[mt][0] * bf2f(qu.x);
        sm = fmaf(acc[mt][1], bf2f(qu.y), sm);
        sm = fmaf(acc[mt][2], bf2f(qu.z), sm);
        sm = fmaf(acc[mt][3], bf2f(qu.w), sm);
        s[mt] = sm;
      }
      float dot = (s[0] + s[1]) + (s[2] + s[3]);
      dot += __shfl_xor(dot, 16, 64);
      dot += __shfl_xor(dot, 32, 64);
      if (quad == 0) dots[rr][bg * 16 + col][cc] = dot;  // stride-4, 2-way: free
    }
  }
  __syncthreads();

  // out-phase: 512 threads -> (b_local = t>>1, rr = t&1); 4 masked scalar stores
  const int ob  = t >> 1;
  const int orr = t & 1;
  const int orx = r0 + orr;
  const f32x4 dv = *(const f32x4*)&dots[orr][ob][0];
  float* orow = out + (size_t)(gb0 + ob) * kP;
  const int ibase = orx * (79 - orx) / 2 - orx - 1;
#pragma unroll
  for (int occ = 0; occ < 4; ++occ) {
    const int ocp = c0 + occ;
    if (ocp > orx) orow[ibase + ocp] = dv[occ];
  }
}

// ---- fallback (no ws): fp32 path ----
__global__ __launch_bounds__(256, 2)
void opn_fp32(const float* __restrict__ inp, const float* __restrict__ param,
              float* __restrict__ out) {
  const int i    = blockIdx.x;
  const int wave = threadIdx.x >> 6;
  const int lane = threadIdx.x & 63;
  const int b    = (blockIdx.y * 4 + wave) * 64 + lane;
  int rem = i, r = 0;
  while (rem >= kN - 1 - r) { rem -= kN - 1 - r; ++r; }
  const int c = r + 1 + rem;
  const float* pb = inp + (size_t)b * (kN * kE) + r * kE;
  const float* qb = inp + (size_t)b * (kN * kE) + c * kE;
  float p[kE];
#pragma unroll
  for (int e = 0; e < kE; ++e) p[e] = pb[e];
  float acc = 0.f;
  for (int f = 0; f < kE; ++f) {
    const float* Mrow = param + ((size_t)f * kP + i) * kE;
    float t0 = 0.f, t1 = 0.f, t2 = 0.f, t3 = 0.f;
#pragma unroll
    for (int e = 0; e < kE; e += 4) {
      t0 = fmaf(Mrow[e + 0], p[e + 0], t0);
      t1 = fmaf(Mrow[e + 1], p[e + 1], t1);
      t2 = fmaf(Mrow[e + 2], p[e + 2], t2);
      t3 = fmaf(Mrow[e + 3], p[e + 3], t3);
    }
    acc = fmaf((t0 + t1) + (t2 + t3), qb[f], acc);
  }
  out[(size_t)b * kP + i] = acc;
}
}  // namespace

extern "C" void kernel_launch(void* const* d_in, const int* in_sizes, int n_in,
                              void* d_out, int out_size, void* d_ws, size_t ws_size,
                              hipStream_t stream) {
  const float* inputs = (const float*)d_in[0];  // (B, N, E) fp32
  const float* param  = (const float*)d_in[1];  // (E, P, E) fp32
  float* out          = (float*)d_out;          // (B, 1, P) fp32

  const size_t xf_bytes = (size_t)kN * kB * kE * sizeof(unsigned short);   // 5.24 MB
  const size_t af_bytes = (size_t)kP * 4096 * sizeof(unsigned short);      // 6.39 MB

  if (ws_size >= xf_bytes + af_bytes) {
    unsigned short* xf = (unsigned short*)d_ws;
    unsigned short* Af = (unsigned short*)((char*)d_ws + xf_bytes);
    prep<<<640 + kP, 256, 0, stream>>>(inputs, param, xf, Af);
    opn_tile2<<<dim3(110, 4), 512, 0, stream>>>(xf, Af, out);
  } else {
    opn_fp32<<<dim3(kP, 4), 256, 0, stream>>>(inputs, param, out);
  }
}

// Round 8
// 88.854 us; speedup vs baseline: 1.0277x; 1.0277x over previous
//
#include <hip/hip_runtime.h>

namespace {
constexpr int kB = 1024;
constexpr int kN = 40;
constexpr int kE = 64;
constexpr int kP = kN * (kN - 1) / 2;  // 780

using bf16x8 = __attribute__((ext_vector_type(8))) short;
using f32x4  = __attribute__((ext_vector_type(4))) float;
using f32x2  = __attribute__((ext_vector_type(2))) float;

__device__ inline unsigned short f2bf(float x) {  // RNE fp32->bf16
  union { float f; unsigned u; } v; v.f = x;
  return (unsigned short)((v.u + 0x7FFFu + ((v.u >> 16) & 1u)) >> 16);
}

// ---- fused prep (R6-proven, unchanged) ----
// blocks [0, 640): x (B,N,E) fp32 -> B-frag layout xf:
//   per (n,bg): 1024 shorts [ks:2][lane:64][j:8] = x[bg*16+(L&15)][n][ks*32+(L>>4)*8+j]
// blocks [640, 1420): param -> A-frag layout Af: per pair i: 4096 shorts,
//   chunk (mt*2+ks)*512 + L*8 holds M_i[16mt+(L&15)][ks*32+(L>>4)*8+j]
__global__ __launch_bounds__(256) void prep(const float* __restrict__ in,
                                            const float* __restrict__ param,
                                            unsigned short* __restrict__ xf,
                                            unsigned short* __restrict__ Af) {
  __shared__ short Ms[64 * 72];
  const int t = threadIdx.x;
  if (blockIdx.x < 640) {
    const int n    = blockIdx.x >> 4;
    const int bgc  = blockIdx.x & 15;
    const int bgl  = t >> 6;
    const int L    = t & 63;
    const int col  = L & 15;
    const int quad = L >> 4;
    const int b    = (bgc * 4 + bgl) * 16 + col;
    const float* src    = in + ((size_t)b * kN + n) * kE + quad * 8;
    unsigned short* dst = xf + (((size_t)n * 64 + bgc * 4 + bgl) << 10) + L * 8;
    const float4 v0 = ((const float4*)src)[0];
    const float4 v1 = ((const float4*)src)[1];
    const float4 v2 = ((const float4*)(src + 32))[0];
    const float4 v3 = ((const float4*)(src + 32))[1];
    bf16x8 o0, o1;
    o0[0] = (short)f2bf(v0.x); o0[1] = (short)f2bf(v0.y);
    o0[2] = (short)f2bf(v0.z); o0[3] = (short)f2bf(v0.w);
    o0[4] = (short)f2bf(v1.x); o0[5] = (short)f2bf(v1.y);
    o0[6] = (short)f2bf(v1.z); o0[7] = (short)f2bf(v1.w);
    o1[0] = (short)f2bf(v2.x); o1[1] = (short)f2bf(v2.y);
    o1[2] = (short)f2bf(v2.z); o1[3] = (short)f2bf(v2.w);
    o1[4] = (short)f2bf(v3.x); o1[5] = (short)f2bf(v3.y);
    o1[6] = (short)f2bf(v3.z); o1[7] = (short)f2bf(v3.w);
    *(bf16x8*)dst         = o0;
    *(bf16x8*)(dst + 512) = o1;
  } else {
    const int i = blockIdx.x - 640;  // pair index
#pragma unroll
    for (int ph = 0; ph < 4; ++ph) {
      const int f  = ph * 16 + (t >> 4);
      const int e0 = (t & 15) * 4;
      const float4 v = *(const float4*)(param + ((size_t)f * kP + i) * kE + e0);
      short* d = &Ms[f * 72 + e0];
      d[0] = (short)f2bf(v.x); d[1] = (short)f2bf(v.y);
      d[2] = (short)f2bf(v.z); d[3] = (short)f2bf(v.w);
    }
    __syncthreads();
    unsigned short* base = Af + (size_t)i * 4096;
#pragma unroll
    for (int u = 0; u < 2; ++u) {
      const int chunk = t * 2 + u;       // 0..511
      const int L    = chunk & 63;
      const int mtks = chunk >> 6;
      const int mt   = mtks >> 1, ks = mtks & 1;
      const int col  = L & 15, quad = L >> 4;
      const bf16x8 a = *(const bf16x8*)&Ms[(16 * mt + col) * 72 + ks * 32 + quad * 8];
      *(bf16x8*)(base + chunk * 8) = a;
    }
  }
}

// ---- main (R6 pair2 structure + depth-2 prefetch ring + packed epilogue) ----
// block = (r, c0..c0+1) x 256 batches; 4 waves = 2 cc x 2 batch-halves, 8 bgs/wave.
__global__ __launch_bounds__(256, 4)
void opn_pair3(const unsigned short* __restrict__ xf,
               const unsigned short* __restrict__ Af,
               float* __restrict__ out) {  // (B,1,P) fp32
  __shared__ float dots[256 * 2];  // [b_local][cc]

  const int t    = threadIdx.x;
  const int w    = t >> 6;
  const int L    = t & 63;
  const int col  = L & 15;
  const int quad = L >> 4;

  // decode blockIdx.x -> (r, c0): rows r=0..38, (40-r)>>1 c-pair tiles each (400 total)
  int tx = blockIdx.x, r = 0;
  for (;;) { const int nq = (40 - r) >> 1; if (tx < nq) break; tx -= nq; ++r; }
  const int c0  = r + 1 + tx * 2;
  const int ib  = r * (79 - r) / 2 + c0 - r - 1;  // pair index of (r, c0)
  const int gb0 = blockIdx.y * 256;

  const int cc = w & 1;
  const int h  = w >> 1;
  const int c  = c0 + cc;

  if (c <= kN - 1) {
    // A-frags: 8 dense 16B loads (HW-verified mapping)
    const unsigned short* ab = Af + (size_t)(ib + cc) * 4096 + L * 8;
    bf16x8 A[4][2];
#pragma unroll
    for (int mt = 0; mt < 4; ++mt)
#pragma unroll
      for (int ks = 0; ks < 2; ++ks)
        A[mt][ks] = *(const bf16x8*)(ab + (mt * 2 + ks) * 512);

    const int bgg0 = blockIdx.y * 16 + h * 8;
    const unsigned short* pb = xf + (((size_t)r * 64 + bgg0) << 10);
    const unsigned short* qb = xf + (((size_t)c * 64 + bgg0) << 10);
    const int qoff = (quad >> 1) * 128 + col * 8 + (quad & 1) * 4;  // 8B-aligned

    // 3-slot ring: prefetch depth 2
    bf16x8 B0[3], B1[3];
    uint2  Qv[3][4];
#pragma unroll
    for (int pf = 0; pf < 2; ++pf) {
      const unsigned short* pn = pb + ((size_t)pf << 10);
      const unsigned short* qn = qb + ((size_t)pf << 10);
      B0[pf]    = *(const bf16x8*)(pn + L * 8);
      B1[pf]    = *(const bf16x8*)(pn + 512 + L * 8);
      Qv[pf][0] = *(const uint2*)(qn + qoff);
      Qv[pf][1] = *(const uint2*)(qn + 256 + qoff);
      Qv[pf][2] = *(const uint2*)(qn + 512 + qoff);
      Qv[pf][3] = *(const uint2*)(qn + 768 + qoff);
    }

#pragma unroll
    for (int bg = 0; bg < 8; ++bg) {
      const int s = bg % 3;
      if (bg < 6) {
        const int ps = (bg + 2) % 3;
        const unsigned short* pn = pb + ((size_t)(bg + 2) << 10);
        const unsigned short* qn = qb + ((size_t)(bg + 2) << 10);
        B0[ps]    = *(const bf16x8*)(pn + L * 8);
        B1[ps]    = *(const bf16x8*)(pn + 512 + L * 8);
        Qv[ps][0] = *(const uint2*)(qn + qoff);
        Qv[ps][1] = *(const uint2*)(qn + 256 + qoff);
        Qv[ps][2] = *(const uint2*)(qn + 512 + qoff);
        Qv[ps][3] = *(const uint2*)(qn + 768 + qoff);
      }
      f32x4 acc[4];
#pragma unroll
      for (int mt = 0; mt < 4; ++mt) acc[mt] = (f32x4){0.f, 0.f, 0.f, 0.f};
#pragma unroll
      for (int mt = 0; mt < 4; ++mt) {
        acc[mt] = __builtin_amdgcn_mfma_f32_16x16x32_bf16(A[mt][0], B0[s], acc[mt], 0, 0, 0);
        acc[mt] = __builtin_amdgcn_mfma_f32_16x16x32_bf16(A[mt][1], B1[s], acc[mt], 0, 0, 0);
      }
      // packed epilogue: q bf16 pairs -> f32x2 via bit-ops, pk-fma accumulate
      f32x2 d2 = (f32x2){0.f, 0.f};
#pragma unroll
      for (int mt = 0; mt < 4; ++mt) {
        const uint2 u = Qv[s][mt];
        const f32x2 qlo = (f32x2){__uint_as_float(u.x << 16),
                                  __uint_as_float(u.x & 0xFFFF0000u)};
        const f32x2 qhi = (f32x2){__uint_as_float(u.y << 16),
                                  __uint_as_float(u.y & 0xFFFF0000u)};
        const f32x2 a01 = (f32x2){acc[mt][0], acc[mt][1]};
        const f32x2 a23 = (f32x2){acc[mt][2], acc[mt][3]};
        d2 = a01 * qlo + d2;  // v_pk_fma_f32
        d2 = a23 * qhi + d2;
      }
      float dot = d2[0] + d2[1];
      dot += __shfl_xor(dot, 16, 64);
      dot += __shfl_xor(dot, 32, 64);
      if (quad == 0) dots[(h * 128 + bg * 16 + col) * 2 + cc] = dot;
    }
  }
  __syncthreads();

  // out-phase: thread t -> batch t; 8B run per b
  const float2 dv = *(const float2*)&dots[t * 2];
  float* ob = out + (size_t)(gb0 + t) * kP + ib;
  ob[0] = dv.x;
  if (c0 + 1 <= kN - 1) ob[1] = dv.y;
}

// ---- fallback (no ws): fp32 path ----
__global__ __launch_bounds__(256, 2)
void opn_fp32(const float* __restrict__ inp, const float* __restrict__ param,
              float* __restrict__ out) {
  const int i    = blockIdx.x;
  const int wave = threadIdx.x >> 6;
  const int lane = threadIdx.x & 63;
  const int b    = (blockIdx.y * 4 + wave) * 64 + lane;
  int rem = i, r = 0;
  while (rem >= kN - 1 - r) { rem -= kN - 1 - r; ++r; }
  const int c = r + 1 + rem;
  const float* pb = inp + (size_t)b * (kN * kE) + r * kE;
  const float* qb = inp + (size_t)b * (kN * kE) + c * kE;
  float p[kE];
#pragma unroll
  for (int e = 0; e < kE; ++e) p[e] = pb[e];
  float acc = 0.f;
  for (int f = 0; f < kE; ++f) {
    const float* Mrow = param + ((size_t)f * kP + i) * kE;
    float t0 = 0.f, t1 = 0.f, t2 = 0.f, t3 = 0.f;
#pragma unroll
    for (int e = 0; e < kE; e += 4) {
      t0 = fmaf(Mrow[e + 0], p[e + 0], t0);
      t1 = fmaf(Mrow[e + 1], p[e + 1], t1);
      t2 = fmaf(Mrow[e + 2], p[e + 2], t2);
      t3 = fmaf(Mrow[e + 3], p[e + 3], t3);
    }
    acc = fmaf((t0 + t1) + (t2 + t3), qb[f], acc);
  }
  out[(size_t)b * kP + i] = acc;
}
}  // namespace

extern "C" void kernel_launch(void* const* d_in, const int* in_sizes, int n_in,
                              void* d_out, int out_size, void* d_ws, size_t ws_size,
                              hipStream_t stream) {
  const float* inputs = (const float*)d_in[0];  // (B, N, E) fp32
  const float* param  = (const float*)d_in[1];  // (E, P, E) fp32
  float* out          = (float*)d_out;          // (B, 1, P) fp32

  const size_t xf_bytes = (size_t)kN * kB * kE * sizeof(unsigned short);   // 5.24 MB
  const size_t af_bytes = (size_t)kP * 4096 * sizeof(unsigned short);      // 6.39 MB

  if (ws_size >= xf_bytes + af_bytes) {
    unsigned short* xf = (unsigned short*)d_ws;
    unsigned short* Af = (unsigned short*)((char*)d_ws + xf_bytes);
    prep<<<640 + kP, 256, 0, stream>>>(inputs, param, xf, Af);
    opn_pair3<<<dim3(400, 4), 256, 0, stream>>>(xf, Af, out);
  } else {
    opn_fp32<<<dim3(kP, 4), 256, 0, stream>>>(inputs, param, out);
  }
}